// Round 10
// baseline (454.498 us; speedup 1.0000x reference)
//
#include <hip/hip_runtime.h>
#include <stdint.h>

#define M_DIM 8192
#define K_DIM 4096
#define N_DIM 4096
#define KTILES (K_DIM / 64)

typedef __attribute__((ext_vector_type(4))) int i32x4;

// ---------------------------------------------------------------------------
// Pack int32-stored int8 weights [N,K] -> true int8 [N,K]; per-row sum folded
// into integer correction corr[n] = (128 - zp) * rowsum[n].
// ---------------------------------------------------------------------------
__global__ void pack_w_kernel(const int* __restrict__ w, char* __restrict__ wp,
                              int* __restrict__ corr, const int* __restrict__ zpp) {
  __shared__ int red[256];
  const int n = blockIdx.x;
  const int t = threadIdx.x;
  const int4* row = (const int4*)(w + (size_t)n * K_DIM);
  int s = 0;
  int words[4];
#pragma unroll
  for (int u = 0; u < 4; ++u) {
    int4 v = row[t * 4 + u];
    s += v.x + v.y + v.z + v.w;
    words[u] = (v.x & 255) | ((v.y & 255) << 8) | ((v.z & 255) << 16) | (v.w << 24);
  }
  ((int4*)(wp + (size_t)n * K_DIM))[t] = make_int4(words[0], words[1], words[2], words[3]);
  red[t] = s;
  __syncthreads();
  for (int off = 128; off > 0; off >>= 1) {
    if (t < off) red[t] += red[t + off];
    __syncthreads();
  }
  if (t == 0) corr[n] = (128 - zpp[0]) * red[0];
}

// ---------------------------------------------------------------------------
// Quantize fp32 input -> int8 (q - 128), 4 elements/thread.
// ---------------------------------------------------------------------------
__global__ void quant_in_kernel(const float* __restrict__ x, char* __restrict__ q,
                                const float* __restrict__ sp, const int* __restrict__ zpp) {
  const int i = blockIdx.x * blockDim.x + threadIdx.x;
  const float s = sp[0];
  const float zp = (float)zpp[0];
  float4 v = ((const float4*)x)[i];
  float t0 = fminf(fmaxf(rintf(v.x / s) + zp, 0.f), 255.f);
  float t1 = fminf(fmaxf(rintf(v.y / s) + zp, 0.f), 255.f);
  float t2 = fminf(fmaxf(rintf(v.z / s) + zp, 0.f), 255.f);
  float t3 = fminf(fmaxf(rintf(v.w / s) + zp, 0.f), 255.f);
  int b0 = (int)t0 - 128, b1 = (int)t1 - 128, b2 = (int)t2 - 128, b3 = (int)t3 - 128;
  ((int*)q)[i] = (b0 & 255) | ((b1 & 255) << 8) | ((b2 & 255) << 16) | (b3 << 24);
}

// ---------------------------------------------------------------------------
// 256x256 i8 GEMM, 4 waves (256 thr), ONE wave per SIMD, 128x128 out/wave.
// Rationale (R3/R6/R9 all ~2540 cyc/tile = LDS+MFMA serial): with 2 waves/
// SIMD in barrier lockstep, both waves sit issue-blocked in their MFMA
// cluster while the LDS unit idles, then both read while matrix idles.
// 1 wave/SIMD + reads-issued-BEFORE-the-cluster lets the LDS unit drain the
// (halved: 64 vs 96 b128/tile, A/B dup 2x/2x) read traffic entirely under
// the 1306-cyc matrix burst. Double frag-sets via 2x unroll (no copies).
// Ring/ledger: 4-slot (A16K+B16K), prefetch dist 3; 8 stages/tile; vmcnt(8)
// at tile end confirms slot t+2; barrier separates a slot's last reads
// (tile t-2) from its overwrite (tile t). Tail: clamped dead re-stages.
// Swizzle (0-conflict, R1-R9): phys 16B slot = g ^ ((row>>1)&3) on both
// staging source and ds_read addr. B content permutation (validated R8/R9):
// LDS row rho holds weight row (rho&~63)+4*(rho&15)+((rho>>4)&3) -> epilogue
// n consecutive per lane -> packed full-line stores (WRITE_SIZE exactly 32MB).
// acc 8x8 frags = 256 VGPR; peak ~420 (<450 no-spill bound, m08).
// ---------------------------------------------------------------------------
#define STAGE16(SRC, DST)                                                     \
  __builtin_amdgcn_global_load_lds(                                           \
      (const __attribute__((address_space(1))) void*)(SRC),                   \
      (__attribute__((address_space(3))) void*)(DST), 16, 0, 0)

#define RD(p) (*(const i32x4*)(p))

#define TILE(T, CA, CB, NA, NB)                                               \
  {                                                                           \
    int rs_ = (T) + 1 < KTILES ? (T) + 1 : KTILES - 1;                        \
    const char* xA_ = &lds[rs_ & 3][0][0];                                    \
    const char* xB_ = &lds[rs_ & 3][1][0];                                    \
    _Pragma("unroll") for (int i_ = 0; i_ < 8; ++i_)                          \
        NA[i_] = RD(xA_ + aoff[i_]);                                          \
    _Pragma("unroll") for (int j_ = 0; j_ < 8; ++j_)                          \
        NB[j_] = RD(xB_ + boff[j_]);                                          \
    const int ks_ = ((T) + 3 < KTILES ? (T) + 3 : KTILES - 1) * 64;           \
    char* nA_ = &lds[((T) + 3) & 3][0][0];                                    \
    char* nB_ = &lds[((T) + 3) & 3][1][0];                                    \
    _Pragma("unroll") for (int c_ = 0; c_ < 4; ++c_) {                        \
      STAGE16(asr[c_] + ks_, nA_ + o_[c_]);                                   \
      STAGE16(bsr[c_] + ks_, nB_ + o_[c_]);                                   \
    }                                                                         \
    __builtin_amdgcn_sched_barrier(0);                                        \
    __builtin_amdgcn_s_setprio(1);                                            \
    _Pragma("unroll") for (int i_ = 0; i_ < 8; ++i_)                          \
        _Pragma("unroll") for (int j_ = 0; j_ < 8; ++j_)                      \
            acc[i_][j_] = __builtin_amdgcn_mfma_i32_16x16x64_i8(              \
                CA[i_], CB[j_], acc[i_][j_], 0, 0, 0);                        \
    __builtin_amdgcn_s_setprio(0);                                            \
    asm volatile("s_waitcnt vmcnt(8)" ::: "memory");                          \
    __builtin_amdgcn_s_barrier();                                             \
  }

template <int WRITE_Q>
__global__ __launch_bounds__(256, 1) void gemm_kernel(
    const char* __restrict__ qa, const char* __restrict__ wb,
    const int* __restrict__ corr, const float* __restrict__ swp,
    const float* __restrict__ bias, const float* __restrict__ sp,
    const int* __restrict__ zpp, char* __restrict__ outq, float* __restrict__ outf) {
  __shared__ __align__(16) char lds[4][2][16384];  // 128 KB: 4-slot ring
  const int tid = threadIdx.x;
  const int lane = tid & 63;
  const int w = tid >> 6;   // 4 waves
  const int wr = w >> 1;    // 0..1 (M)
  const int wc = w & 1;     // 0..1 (N)
  const int bid = blockIdx.x;
  const int bm = bid & 31;  // M/256 = 32, fastest: neighbors share B panel
  const int bn = bid >> 5;  // N/256 = 16
  const char* abase = qa + (size_t)bm * 256 * K_DIM;
  const char* bbase = wb + (size_t)bn * 256 * K_DIM;

  // --- staging constants: 4 chunks of 4 KB (256 thr x 16 B) cover 16 KB ---
  int o_[4];
  const char* asr[4];
  const char* bsr[4];
#pragma unroll
  for (int c = 0; c < 4; ++c) {
    o_[c] = c * 4096 + tid * 16;
    const int rc = o_[c] >> 6;                       // tile row of this 16B
    const int gc = (tid & 3) ^ ((rc >> 1) & 3);      // inverse-swizzled slot
    const int pc = (rc & ~63) + 4 * (rc & 15) + ((rc >> 4) & 3);  // B perm
    asr[c] = abase + (size_t)rc * K_DIM + gc * 16;
    bsr[c] = bbase + (size_t)pc * K_DIM + gc * 16;
  }

  // --- per-lane ds_read byte offsets (swizzled) ---
  const int rr = lane & 15;
  const int g = lane >> 4;
  int aoff[8], boff[8];
#pragma unroll
  for (int i = 0; i < 8; ++i) {
    const int rowA = wr * 128 + i * 16 + rr;
    aoff[i] = (rowA << 6) + ((g ^ ((rowA >> 1) & 3)) << 4);
    const int rowB = wc * 128 + i * 16 + rr;
    boff[i] = (rowB << 6) + ((g ^ ((rowB >> 1) & 3)) << 4);
  }

  i32x4 acc[8][8] = {};

  // --- prologue: stage slots 0,1,2 (24 ops); vmcnt(16) confirms slot 0 ---
#pragma unroll
  for (int s_ = 0; s_ < 3; ++s_) {
#pragma unroll
    for (int c = 0; c < 4; ++c) {
      STAGE16(asr[c] + s_ * 64, &lds[s_][0][o_[c]]);
      STAGE16(bsr[c] + s_ * 64, &lds[s_][1][o_[c]]);
    }
  }
  asm volatile("s_waitcnt vmcnt(16)" ::: "memory");  // slot 0 confirmed
  __builtin_amdgcn_s_barrier();

  i32x4 ca[8], cb[8], na[8], nb[8];
#pragma unroll
  for (int i = 0; i < 8; ++i) {
    ca[i] = RD(&lds[0][0][0] + aoff[i]);
    cb[i] = RD(&lds[0][1][0] + boff[i]);
  }

  // --- main loop: 64 tiles, unroll 2 (alternating frag sets, no copies) ---
  for (int tb = 0; tb < KTILES / 2; ++tb) {
    const int t0 = tb * 2;
    TILE(t0, ca, cb, na, nb)
    TILE(t0 + 1, na, nb, ca, cb)
  }
  asm volatile("s_waitcnt vmcnt(0)" ::: "memory");  // drain before exit

  // --- epilogue: frag j<4 -> n = nb4+j; frag j>=4 -> n = nb4+64+(j-4) ---
  const float s = sp[0];
  const float zpf = (float)zpp[0];
  const int m0 = bm * 256 + wr * 128 + (lane >> 4) * 4;
  const int nb4 = bn * 256 + wc * 128 + ((lane & 15) << 2);
  const int4 crA = *(const int4*)(corr + nb4);
  const int4 crB = *(const int4*)(corr + nb4 + 64);
  const float4 swA = *(const float4*)(swp + nb4);
  const float4 swB = *(const float4*)(swp + nb4 + 64);
  const float4 bbA = *(const float4*)(bias + nb4);
  const float4 bbB = *(const float4*)(bias + nb4 + 64);
#pragma unroll
  for (int i = 0; i < 8; ++i) {
#pragma unroll
    for (int q = 0; q < 4; ++q) {
      const int m = m0 + i * 16 + q;
      const float vA0 = s * swA.x * (float)(acc[i][0][q] + crA.x) + bbA.x;
      const float vA1 = s * swA.y * (float)(acc[i][1][q] + crA.y) + bbA.y;
      const float vA2 = s * swA.z * (float)(acc[i][2][q] + crA.z) + bbA.z;
      const float vA3 = s * swA.w * (float)(acc[i][3][q] + crA.w) + bbA.w;
      const float vB0 = s * swB.x * (float)(acc[i][4][q] + crB.x) + bbB.x;
      const float vB1 = s * swB.y * (float)(acc[i][5][q] + crB.y) + bbB.y;
      const float vB2 = s * swB.z * (float)(acc[i][6][q] + crB.z) + bbB.z;
      const float vB3 = s * swB.w * (float)(acc[i][7][q] + crB.w) + bbB.w;
      if (WRITE_Q) {
        const int a0i = (int)fminf(fmaxf(rintf(vA0 / s) + zpf, 0.f), 255.f) - 128;
        const int a1i = (int)fminf(fmaxf(rintf(vA1 / s) + zpf, 0.f), 255.f) - 128;
        const int a2i = (int)fminf(fmaxf(rintf(vA2 / s) + zpf, 0.f), 255.f) - 128;
        const int a3i = (int)fminf(fmaxf(rintf(vA3 / s) + zpf, 0.f), 255.f) - 128;
        const int b0i = (int)fminf(fmaxf(rintf(vB0 / s) + zpf, 0.f), 255.f) - 128;
        const int b1i = (int)fminf(fmaxf(rintf(vB1 / s) + zpf, 0.f), 255.f) - 128;
        const int b2i = (int)fminf(fmaxf(rintf(vB2 / s) + zpf, 0.f), 255.f) - 128;
        const int b3i = (int)fminf(fmaxf(rintf(vB3 / s) + zpf, 0.f), 255.f) - 128;
        const uint32_t pkA = (uint32_t)(a0i & 255) | ((uint32_t)(a1i & 255) << 8) |
                             ((uint32_t)(a2i & 255) << 16) | ((uint32_t)a3i << 24);
        const uint32_t pkB = (uint32_t)(b0i & 255) | ((uint32_t)(b1i & 255) << 8) |
                             ((uint32_t)(b2i & 255) << 16) | ((uint32_t)b3i << 24);
        *(uint32_t*)(outq + (size_t)m * N_DIM + nb4) = pkA;
        *(uint32_t*)(outq + (size_t)m * N_DIM + nb4 + 64) = pkB;
      } else {
        float4 oA, oB;
        oA.x = vA0; oA.y = vA1; oA.z = vA2; oA.w = vA3;
        oB.x = vB0; oB.y = vB1; oB.z = vB2; oB.w = vB3;
        *(float4*)(outf + (size_t)m * N_DIM + nb4) = oA;
        *(float4*)(outf + (size_t)m * N_DIM + nb4 + 64) = oB;
      }
    }
  }
}

// ---------------------------------------------------------------------------
extern "C" void kernel_launch(void* const* d_in, const int* in_sizes, int n_in,
                              void* d_out, int out_size, void* d_ws, size_t ws_size,
                              hipStream_t stream) {
  const float* x = (const float*)d_in[0];
  const int* wq = (const int*)d_in[1];
  const float* bias = (const float*)d_in[2];
  const float* s_in = (const float*)d_in[3];
  const int* zp_in = (const int*)d_in[4];
  const float* s_w = (const float*)d_in[5];
  float* out = (float*)d_out;

  const size_t WP_BYTES = (size_t)N_DIM * K_DIM;  // 16 MB packed int8 W
  const size_t Q_BYTES = (size_t)M_DIM * K_DIM;   // 32 MB int8 activations
  char* ws = (char*)d_ws;
  char* wp = ws;
  char* q1 = ws + WP_BYTES;
  char* q2 = q1 + Q_BYTES;
  int* corr = (int*)(q2 + Q_BYTES);
  const size_t NEEDED = WP_BYTES + 2 * Q_BYTES + (size_t)N_DIM * sizeof(int);
  if (ws_size < NEEDED) return;

  pack_w_kernel<<<N_DIM, 256, 0, stream>>>(wq, wp, corr, zp_in);
  quant_in_kernel<<<(M_DIM * K_DIM / 4) / 256, 256, 0, stream>>>(x, q1, s_in, zp_in);

  dim3 grid((M_DIM / 256) * (N_DIM / 256));  // 512 blocks
  dim3 blk(256);
  gemm_kernel<1><<<grid, blk, 0, stream>>>(q1, wp, corr, s_w, bias, s_in, zp_in, q2, nullptr);
  gemm_kernel<1><<<grid, blk, 0, stream>>>(q2, wp, corr, s_w, bias, s_in, zp_in, q1, nullptr);
  gemm_kernel<0><<<grid, blk, 0, stream>>>(q1, wp, corr, s_w, bias, s_in, zp_in, nullptr, out);
}